// Round 6
// baseline (224.356 us; speedup 1.0000x reference)
//
#include <hip/hip_runtime.h>

// MHA forward: B=2 T=2048 C=1024 H=16 D=64, causal, scale 1/sqrt(C)=1/32
// cast -> QKV gemm (2-phase dbuf LDS, Q pre-scaled by 1/32*log2e) ->
// flash attn (1 rowset/wave, swapped QK^T, exp2, defer-max, XCD clustering) -> out gemm

#define Bsz 2
#define Tsz 2048
#define Cdim 1024
#define Hn 16
#define Dh 64

typedef short bf16x8 __attribute__((ext_vector_type(8)));
typedef float f32x4 __attribute__((ext_vector_type(4)));
typedef unsigned short u16;

#define MFMA(a, b, c) __builtin_amdgcn_mfma_f32_16x16x32_bf16(a, b, c, 0, 0, 0)
#define NEGINF (-__builtin_inff())

#define GLD16(g, l)                                                            \
  __builtin_amdgcn_global_load_lds((const __attribute__((address_space(1))) void*)(g), \
                                   (__attribute__((address_space(3))) void*)(l), 16, 0, 0)

__device__ __forceinline__ u16 f2bf(float f) {
  unsigned u = __builtin_bit_cast(unsigned, f);
  unsigned r = 0x7fffu + ((u >> 16) & 1u);
  return (u16)((u + r) >> 16);
}

// pack two f32 -> one u32 of 2x bf16 (RNE, plain int ops)
__device__ __forceinline__ unsigned pkbf(float lo, float hi) {
  return (unsigned)f2bf(lo) | ((unsigned)f2bf(hi) << 16);
}

// flat f32 -> bf16 cast, 4 elems/thread
__global__ __launch_bounds__(256) void k_cast_x(const float* __restrict__ x,
                                                u16* __restrict__ xb, int n4) {
  int i = blockIdx.x * 256 + threadIdx.x;
  if (i >= n4) return;
  float4 v = reinterpret_cast<const float4*>(x)[i];
  ushort4 o;
  o.x = f2bf(v.x); o.y = f2bf(v.y); o.z = f2bf(v.z); o.w = f2bf(v.w);
  reinterpret_cast<ushort4*>(xb)[i] = o;
}

// Wq/Wk/Wv [H][C][D] f32 -> wt [(m*H+h)*D+d][C] bf16 via LDS tile transpose.
__global__ __launch_bounds__(256) void k_cast_w(const float* __restrict__ Wq,
                                                const float* __restrict__ Wk,
                                                const float* __restrict__ Wv,
                                                u16* __restrict__ wt) {
  __shared__ u16 tile[64][68];
  const int mh = blockIdx.y;  // 0..47
  const int m = mh >> 4, h = mh & 15;
  const float* src = (m == 0 ? Wq : m == 1 ? Wk : Wv) + (size_t)h * Cdim * Dh;
  const int c0 = blockIdx.x * 64;
  const int tid = threadIdx.x;
  const int cc = tid >> 4, d4 = (tid & 15) * 4;
#pragma unroll
  for (int i = 0; i < 4; ++i) {
    int c = i * 16 + cc;
    float4 v = *(const float4*)(src + (size_t)(c0 + c) * Dh + d4);
    tile[d4 + 0][c] = f2bf(v.x);
    tile[d4 + 1][c] = f2bf(v.y);
    tile[d4 + 2][c] = f2bf(v.z);
    tile[d4 + 3][c] = f2bf(v.w);
  }
  __syncthreads();
  const int c4 = (tid & 15) * 4, dd = tid >> 4;
#pragma unroll
  for (int i = 0; i < 4; ++i) {
    int d = i * 16 + dd;
    ushort4 o;
    o.x = tile[d][c4]; o.y = tile[d][c4 + 1];
    o.z = tile[d][c4 + 2]; o.w = tile[d][c4 + 3];
    *(ushort4*)(wt + (size_t)(mh * 64 + d) * Cdim + c0 + c4) = o;
  }
}

// QKV GEMM, 2-phase double-buffered: 128x128 tile, BK=32, global_load_lds(16B).
__global__ __launch_bounds__(256) void k_gemm_qkv(const u16* __restrict__ xb,
                                                  const u16* __restrict__ wt,
                                                  u16* __restrict__ qb,
                                                  u16* __restrict__ kb,
                                                  u16* __restrict__ vtb) {
  __shared__ __align__(16) u16 As[2][4096], Bs[2][4096];
  const int tid = threadIdx.x, lane = tid & 63, wid = tid >> 6;
  const int cl = lane & 15, kg = lane >> 4;
  const int row0 = blockIdx.y * 128, col0 = blockIdx.x * 128;
  const int wrow = (wid >> 1) * 64, wcol = (wid & 1) * 64;
  f32x4 acc[4][4] = {};
  const u16* a_src = xb + (size_t)(row0 + 32 * wid + (lane >> 2)) * Cdim + (lane & 3) * 8;
  const u16* b_src = wt + (size_t)(col0 + 32 * wid + (lane >> 2)) * Cdim + (lane & 3) * 8;

  auto stage = [&](int buf, int ke) {
    u16* Ad = &As[buf][1024 * wid];
    u16* Bd = &Bs[buf][1024 * wid];
    GLD16(a_src + ke, Ad);
    GLD16(a_src + 16 * Cdim + ke, Ad + 512);
    GLD16(b_src + ke, Bd);
    GLD16(b_src + 16 * Cdim + ke, Bd + 512);
  };

  stage(0, 0);
  __syncthreads();
  int cur = 0;
  for (int kk = 0; kk < 32; ++kk) {
    if (kk < 31) stage(cur ^ 1, (kk + 1) * 32);
    const u16* ar = &As[cur][(wrow + cl) * 32 + kg * 8];
    const u16* br = &Bs[cur][(wcol + cl) * 32 + kg * 8];
    bf16x8 af[4], bfr[4];
#pragma unroll
    for (int mi = 0; mi < 4; ++mi) af[mi] = *(const bf16x8*)(ar + mi * 512);
#pragma unroll
    for (int ni = 0; ni < 4; ++ni) bfr[ni] = *(const bf16x8*)(br + ni * 512);
#pragma unroll
    for (int mi = 0; mi < 4; ++mi)
#pragma unroll
      for (int ni = 0; ni < 4; ++ni)
        acc[mi][ni] = MFMA(af[mi], bfr[ni], acc[mi][ni]);
    __syncthreads();
    cur ^= 1;
  }
#pragma unroll
  for (int mi = 0; mi < 4; ++mi) {
#pragma unroll
    for (int ni = 0; ni < 4; ++ni) {
      int n = col0 + wcol + ni * 16 + cl;
      int m = n >> 10, h = (n >> 6) & 15, d = n & 63;
#pragma unroll
      for (int j = 0; j < 4; ++j) {
        int r = row0 + wrow + mi * 16 + kg * 4 + j;
        int b = r >> 11, t = r & 2047;
        float av = acc[mi][ni][j];
        if (m == 0) av *= 0.04508422f;  // 1/sqrt(C) * log2(e) folded into Q
        u16 v = f2bf(av);
        size_t bh = (size_t)(b * Hn + h);
        if (m == 0)
          qb[(bh * Tsz + t) * Dh + d] = v;
        else if (m == 1)
          kb[(bh * Tsz + t) * Dh + d] = v;
        else
          vtb[(bh * Dh + d) * Tsz + t] = v;
      }
    }
  }
}

// ---- flash attention (1 rowset/wave, swapped QK^T, exp2, defer-max) ----

__device__ __forceinline__ void load_k(const u16* __restrict__ Kp, int k0,
                                       int cl, int kg, bf16x8 kf[8]) {
#pragma unroll
  for (int nt = 0; nt < 4; ++nt) {
    const u16* kp = Kp + (size_t)(k0 + nt * 16 + cl) * Dh + kg * 8;
    kf[nt * 2] = *(const bf16x8*)kp;
    kf[nt * 2 + 1] = *(const bf16x8*)(kp + 32);
  }
}

__device__ __forceinline__ void load_v(const u16* __restrict__ Vp, int k0,
                                       int cl, int kg, bf16x8 vf[8]) {
#pragma unroll
  for (int dt = 0; dt < 4; ++dt) {
    const u16* vp = Vp + (size_t)(dt * 16 + cl) * Tsz + k0 + kg * 8;
    vf[dt * 2] = *(const bf16x8*)vp;
    vf[dt * 2 + 1] = *(const bf16x8*)(vp + 32);
  }
}

// Grid: 1024 flat blocks. bid&7 = XCD; s = bid>>3; t = 31-(s>>2) (longest
// first); bh p = (bid&7) + 8*(s&3). 4 waves/block, wave wid owns q-rows
// [t*64+wid*16, +16). All blocks of one (b,h) share an XCD (KV L2-resident).
__global__ __launch_bounds__(256, 4) void k_attn(const u16* __restrict__ qb,
                                                 const u16* __restrict__ kb,
                                                 const u16* __restrict__ vtb,
                                                 u16* __restrict__ ob) {
  __shared__ __align__(16) u16 Plds[4][1024];
  const int lane = threadIdx.x & 63, wid = threadIdx.x >> 6;
  const int cl = lane & 15, kg = lane >> 4;
  const int s = blockIdx.x >> 3;
  const int t = 31 - (s >> 2);
  const int p = (blockIdx.x & 7) + 8 * (s & 3);
  const int h = p & 15, b = p >> 4;
  const int qr = t * 64 + wid * 16;
  const size_t bh = (size_t)(b * Hn + h);
  const u16* Qp = qb + bh * Tsz * Dh;
  const u16* Kp = kb + bh * Tsz * Dh;
  const u16* Vp = vtb + bh * Dh * Tsz;

  bf16x8 qa0 = *(const bf16x8*)(Qp + (size_t)(qr + cl) * Dh + kg * 8);
  bf16x8 qa1 = *(const bf16x8*)(Qp + (size_t)(qr + cl) * Dh + 32 + kg * 8);

  f32x4 o[4] = {};
  float m = NEGINF, l = 0.f;

  char* pb = (char*)&Plds[wid][0];
  const int rdoff0 = ((cl << 7) + (kg << 4)) ^ ((cl & 7) << 4);
  const int rdoff1 = ((cl << 7) + 64 + (kg << 4)) ^ ((cl & 7) << 4);
  const int rowoff = wid * 16;

  for (int kt = 0; kt <= t; ++kt) {
    const int k0 = kt * 64;
    bf16x8 kf[8], vf[8];
    load_k(Kp, k0, cl, kg, kf);
    load_v(Vp, k0, cl, kg, vf);
    f32x4 sv[4];
    __builtin_amdgcn_s_setprio(1);
#pragma unroll
    for (int nt = 0; nt < 4; ++nt) {
      f32x4 z = {};
      z = MFMA(kf[nt * 2], qa0, z);
      z = MFMA(kf[nt * 2 + 1], qa1, z);
      sv[nt] = z;
    }
    __builtin_amdgcn_s_setprio(0);
    if (kt == t) {  // diag tile: mask col > row
#pragma unroll
      for (int nt = 0; nt < 4; ++nt)
#pragma unroll
        for (int j = 0; j < 4; ++j)
          if (nt * 16 + kg * 4 + j > rowoff + cl) sv[nt][j] = NEGINF;
    }
    float t0 = fmaxf(fmaxf(fmaxf(sv[0][0], sv[0][1]), fmaxf(sv[0][2], sv[0][3])),
                     fmaxf(fmaxf(sv[1][0], sv[1][1]), fmaxf(sv[1][2], sv[1][3])));
    float t1 = fmaxf(fmaxf(fmaxf(sv[2][0], sv[2][1]), fmaxf(sv[2][2], sv[2][3])),
                     fmaxf(fmaxf(sv[3][0], sv[3][1]), fmaxf(sv[3][2], sv[3][3])));
    float tm = fmaxf(t0, t1);
    tm = fmaxf(tm, __shfl_xor(tm, 16));
    tm = fmaxf(tm, __shfl_xor(tm, 32));
    // defer-max: skip rescale when tile max doesn't raise m by >8 (P <= 2^8)
    if (!__all(tm <= m + 8.0f)) {
      float mnew = fmaxf(m, tm);
      float corr = exp2f(m - mnew);
      m = mnew;
      l *= corr;
      float c0 = __shfl(corr, kg * 4 + 0);
      float c1 = __shfl(corr, kg * 4 + 1);
      float c2 = __shfl(corr, kg * 4 + 2);
      float c3 = __shfl(corr, kg * 4 + 3);
#pragma unroll
      for (int dt = 0; dt < 4; ++dt) {
        o[dt][0] *= c0; o[dt][1] *= c1; o[dt][2] *= c2; o[dt][3] *= c3;
      }
    }
    float rs = 0.f;
#pragma unroll
    for (int nt = 0; nt < 4; ++nt)
#pragma unroll
      for (int j = 0; j < 4; ++j) {
        float pv = exp2f(sv[nt][j] - m);
        sv[nt][j] = pv;
        rs += pv;
      }
    // P -> LDS rows [q=cl][k], packed bf16x2, 8B stores, XOR-swizzled
#pragma unroll
    for (int nt = 0; nt < 4; ++nt) {
      uint2 pk;
      pk.x = pkbf(sv[nt][0], sv[nt][1]);
      pk.y = pkbf(sv[nt][2], sv[nt][3]);
      int waddr = ((cl << 7) + (nt << 5) + (kg << 3)) ^ ((cl & 7) << 4);
      *(uint2*)(pb + waddr) = pk;
    }
    rs += __shfl_xor(rs, 16);
    rs += __shfl_xor(rs, 32);
    l += rs;
    bf16x8 pa0 = *(const bf16x8*)(pb + rdoff0);
    bf16x8 pa1 = *(const bf16x8*)(pb + rdoff1);
    __builtin_amdgcn_s_setprio(1);
#pragma unroll
    for (int dt = 0; dt < 4; ++dt) {
      o[dt] = MFMA(pa0, vf[dt * 2], o[dt]);
      o[dt] = MFMA(pa1, vf[dt * 2 + 1], o[dt]);
    }
    __builtin_amdgcn_s_setprio(0);
  }

  float i0 = 1.f / __shfl(l, kg * 4 + 0), i1 = 1.f / __shfl(l, kg * 4 + 1);
  float i2 = 1.f / __shfl(l, kg * 4 + 2), i3 = 1.f / __shfl(l, kg * 4 + 3);
  float inv[4] = {i0, i1, i2, i3};
#pragma unroll
  for (int dt = 0; dt < 4; ++dt)
#pragma unroll
    for (int j = 0; j < 4; ++j) {
      int tr = qr + kg * 4 + j;
      ob[(size_t)(b * Tsz + tr) * Cdim + h * Dh + dt * 16 + cl] = f2bf(o[dt][j] * inv[j]);
    }
}

// Out GEMM, 2-phase dbuf: 128x64 tile, BK=32.
__global__ __launch_bounds__(256) void k_gemm_out(const u16* __restrict__ ob,
                                                  const u16* __restrict__ wob,
                                                  const float* __restrict__ bo,
                                                  float* __restrict__ out) {
  __shared__ __align__(16) u16 As[2][4096], Bs[2][2048];
  const int tid = threadIdx.x, lane = tid & 63, wid = tid >> 6;
  const int cl = lane & 15, kg = lane >> 4;
  const int row0 = blockIdx.y * 128, col0 = blockIdx.x * 64;
  const int wrow = (wid >> 1) * 64, wcol = (wid & 1) * 32;
  f32x4 acc[4][2] = {};
  const u16* a_src = ob + (size_t)(row0 + 32 * wid + (lane >> 2)) * Cdim + (lane & 3) * 8;
  const u16* b_src = wob + (size_t)(col0 + 16 * wid + (lane >> 2)) * Cdim + (lane & 3) * 8;

  auto stage = [&](int buf, int ke) {
    u16* Ad = &As[buf][1024 * wid];
    u16* Bd = &Bs[buf][512 * wid];
    GLD16(a_src + ke, Ad);
    GLD16(a_src + 16 * Cdim + ke, Ad + 512);
    GLD16(b_src + ke, Bd);
  };

  stage(0, 0);
  __syncthreads();
  int cur = 0;
  for (int kk = 0; kk < 32; ++kk) {
    if (kk < 31) stage(cur ^ 1, (kk + 1) * 32);
    const u16* ar = &As[cur][(wrow + cl) * 32 + kg * 8];
    const u16* br = &Bs[cur][(wcol + cl) * 32 + kg * 8];
    bf16x8 af[4], bfr[2];
#pragma unroll
    for (int mi = 0; mi < 4; ++mi) af[mi] = *(const bf16x8*)(ar + mi * 512);
#pragma unroll
    for (int ni = 0; ni < 2; ++ni) bfr[ni] = *(const bf16x8*)(br + ni * 512);
#pragma unroll
    for (int mi = 0; mi < 4; ++mi)
#pragma unroll
      for (int ni = 0; ni < 2; ++ni)
        acc[mi][ni] = MFMA(af[mi], bfr[ni], acc[mi][ni]);
    __syncthreads();
    cur ^= 1;
  }
#pragma unroll
  for (int mi = 0; mi < 4; ++mi) {
#pragma unroll
    for (int ni = 0; ni < 2; ++ni) {
      int n = col0 + wcol + ni * 16 + cl;
      float bias = bo[n];
#pragma unroll
      for (int j = 0; j < 4; ++j) {
        int r = row0 + wrow + mi * 16 + kg * 4 + j;
        out[(size_t)r * Cdim + n] = acc[mi][ni][j] + bias;
      }
    }
  }
}

extern "C" void kernel_launch(void* const* d_in, const int* in_sizes, int n_in,
                              void* d_out, int out_size, void* d_ws, size_t ws_size,
                              hipStream_t stream) {
  (void)in_sizes; (void)n_in; (void)out_size; (void)ws_size;
  const float* x = (const float*)d_in[0];
  const float* Wq = (const float*)d_in[1];
  const float* Wk = (const float*)d_in[2];
  const float* Wv = (const float*)d_in[3];
  const float* Wo = (const float*)d_in[4];
  const float* bo = (const float*)d_in[5];
  float* out = (float*)d_out;
  char* ws = (char*)d_ws;
  u16* xb = (u16*)(ws);                  // 8 MiB  x bf16 [4096][1024]
  u16* wt = (u16*)(ws + (8u << 20));     // 6 MiB  Wqkv^T bf16 [3072][1024]
  u16* wob = (u16*)(ws + (14u << 20));   // 2 MiB  Wo bf16 [1024][1024]
  u16* qb = (u16*)(ws + (16u << 20));    // 8 MiB  Q [b][h][t][d] (pre-scaled)
  u16* kb = (u16*)(ws + (24u << 20));    // 8 MiB  K [b][h][t][d]
  u16* vtb = (u16*)(ws + (32u << 20));   // 8 MiB  V^T [b][h][d][t]
  u16* ob = (u16*)(ws + (40u << 20));    // 8 MiB  attn out [b][t][h*64+d]

  k_cast_x<<<4096, 256, 0, stream>>>(x, xb, Bsz * Tsz * Cdim / 4);
  k_cast_x<<<1024, 256, 0, stream>>>(Wo, wob, Cdim * Cdim / 4);
  k_cast_w<<<dim3(16, 48), 256, 0, stream>>>(Wq, Wk, Wv, wt);
  k_gemm_qkv<<<dim3(24, 32), 256, 0, stream>>>(xb, wt, qb, kb, vtb);
  k_attn<<<1024, 256, 0, stream>>>(qb, kb, vtb, ob);
  k_gemm_out<<<dim3(16, 32), 256, 0, stream>>>(ob, wob, bo, out);
}

// Round 7
// 197.852 us; speedup vs baseline: 1.1340x; 1.1340x over previous
//
#include <hip/hip_runtime.h>

// MHA forward: B=2 T=2048 C=1024 H=16 D=64, causal, scale 1/sqrt(C)=1/32
// cast -> QKV gemm (2-phase dbuf LDS, Q pre-scaled by 1/32*log2e) ->
// folded flash attn (dual rowset/wave, swapped QK^T, native exp2, lazy
// reductions, defer-max, XCD clustering) -> out gemm

#define Bsz 2
#define Tsz 2048
#define Cdim 1024
#define Hn 16
#define Dh 64

typedef short bf16x8 __attribute__((ext_vector_type(8)));
typedef float f32x4 __attribute__((ext_vector_type(4)));
typedef unsigned short u16;

#define MFMA(a, b, c) __builtin_amdgcn_mfma_f32_16x16x32_bf16(a, b, c, 0, 0, 0)
#define NEGINF (-__builtin_inff())
#define EXP2(x) __builtin_amdgcn_exp2f(x)

#define GLD16(g, l)                                                            \
  __builtin_amdgcn_global_load_lds((const __attribute__((address_space(1))) void*)(g), \
                                   (__attribute__((address_space(3))) void*)(l), 16, 0, 0)

__device__ __forceinline__ u16 f2bf(float f) {
  unsigned u = __builtin_bit_cast(unsigned, f);
  unsigned r = 0x7fffu + ((u >> 16) & 1u);
  return (u16)((u + r) >> 16);
}

// packed f32x2 -> bf16x2 via hardware cvt_pk (RNE)
__device__ __forceinline__ unsigned cvtpk(float lo, float hi) {
  unsigned r;
  asm("v_cvt_pk_bf16_f32 %0, %1, %2" : "=v"(r) : "v"(lo), "v"(hi));
  return r;
}

// flat f32 -> bf16 cast, 4 elems/thread
__global__ __launch_bounds__(256) void k_cast_x(const float* __restrict__ x,
                                                u16* __restrict__ xb, int n4) {
  int i = blockIdx.x * 256 + threadIdx.x;
  if (i >= n4) return;
  float4 v = reinterpret_cast<const float4*>(x)[i];
  ushort4 o;
  o.x = f2bf(v.x); o.y = f2bf(v.y); o.z = f2bf(v.z); o.w = f2bf(v.w);
  reinterpret_cast<ushort4*>(xb)[i] = o;
}

// Wq/Wk/Wv [H][C][D] f32 -> wt [(m*H+h)*D+d][C] bf16 via LDS tile transpose.
__global__ __launch_bounds__(256) void k_cast_w(const float* __restrict__ Wq,
                                                const float* __restrict__ Wk,
                                                const float* __restrict__ Wv,
                                                u16* __restrict__ wt) {
  __shared__ u16 tile[64][68];
  const int mh = blockIdx.y;  // 0..47
  const int m = mh >> 4, h = mh & 15;
  const float* src = (m == 0 ? Wq : m == 1 ? Wk : Wv) + (size_t)h * Cdim * Dh;
  const int c0 = blockIdx.x * 64;
  const int tid = threadIdx.x;
  const int cc = tid >> 4, d4 = (tid & 15) * 4;
#pragma unroll
  for (int i = 0; i < 4; ++i) {
    int c = i * 16 + cc;
    float4 v = *(const float4*)(src + (size_t)(c0 + c) * Dh + d4);
    tile[d4 + 0][c] = f2bf(v.x);
    tile[d4 + 1][c] = f2bf(v.y);
    tile[d4 + 2][c] = f2bf(v.z);
    tile[d4 + 3][c] = f2bf(v.w);
  }
  __syncthreads();
  const int c4 = (tid & 15) * 4, dd = tid >> 4;
#pragma unroll
  for (int i = 0; i < 4; ++i) {
    int d = i * 16 + dd;
    ushort4 o;
    o.x = tile[d][c4]; o.y = tile[d][c4 + 1];
    o.z = tile[d][c4 + 2]; o.w = tile[d][c4 + 3];
    *(ushort4*)(wt + (size_t)(mh * 64 + d) * Cdim + c0 + c4) = o;
  }
}

// QKV GEMM, 2-phase double-buffered: 128x128 tile, BK=32, global_load_lds(16B).
__global__ __launch_bounds__(256) void k_gemm_qkv(const u16* __restrict__ xb,
                                                  const u16* __restrict__ wt,
                                                  u16* __restrict__ qb,
                                                  u16* __restrict__ kb,
                                                  u16* __restrict__ vtb) {
  __shared__ __align__(16) u16 As[2][4096], Bs[2][4096];
  const int tid = threadIdx.x, lane = tid & 63, wid = tid >> 6;
  const int cl = lane & 15, kg = lane >> 4;
  const int row0 = blockIdx.y * 128, col0 = blockIdx.x * 128;
  const int wrow = (wid >> 1) * 64, wcol = (wid & 1) * 64;
  f32x4 acc[4][4] = {};
  const u16* a_src = xb + (size_t)(row0 + 32 * wid + (lane >> 2)) * Cdim + (lane & 3) * 8;
  const u16* b_src = wt + (size_t)(col0 + 32 * wid + (lane >> 2)) * Cdim + (lane & 3) * 8;

  auto stage = [&](int buf, int ke) {
    u16* Ad = &As[buf][1024 * wid];
    u16* Bd = &Bs[buf][1024 * wid];
    GLD16(a_src + ke, Ad);
    GLD16(a_src + 16 * Cdim + ke, Ad + 512);
    GLD16(b_src + ke, Bd);
    GLD16(b_src + 16 * Cdim + ke, Bd + 512);
  };

  stage(0, 0);
  __syncthreads();
  int cur = 0;
  for (int kk = 0; kk < 32; ++kk) {
    if (kk < 31) stage(cur ^ 1, (kk + 1) * 32);
    const u16* ar = &As[cur][(wrow + cl) * 32 + kg * 8];
    const u16* br = &Bs[cur][(wcol + cl) * 32 + kg * 8];
    bf16x8 af[4], bfr[4];
#pragma unroll
    for (int mi = 0; mi < 4; ++mi) af[mi] = *(const bf16x8*)(ar + mi * 512);
#pragma unroll
    for (int ni = 0; ni < 4; ++ni) bfr[ni] = *(const bf16x8*)(br + ni * 512);
#pragma unroll
    for (int mi = 0; mi < 4; ++mi)
#pragma unroll
      for (int ni = 0; ni < 4; ++ni)
        acc[mi][ni] = MFMA(af[mi], bfr[ni], acc[mi][ni]);
    __syncthreads();
    cur ^= 1;
  }
#pragma unroll
  for (int mi = 0; mi < 4; ++mi) {
#pragma unroll
    for (int ni = 0; ni < 4; ++ni) {
      int n = col0 + wcol + ni * 16 + cl;
      int m = n >> 10, h = (n >> 6) & 15, d = n & 63;
#pragma unroll
      for (int j = 0; j < 4; ++j) {
        int r = row0 + wrow + mi * 16 + kg * 4 + j;
        int b = r >> 11, t = r & 2047;
        float av = acc[mi][ni][j];
        if (m == 0) av *= 0.04508422f;  // 1/sqrt(C) * log2(e) folded into Q
        u16 v = f2bf(av);
        size_t bh = (size_t)(b * Hn + h);
        if (m == 0)
          qb[(bh * Tsz + t) * Dh + d] = v;
        else if (m == 1)
          kb[(bh * Tsz + t) * Dh + d] = v;
        else
          vtb[(bh * Dh + d) * Tsz + t] = v;
      }
    }
  }
}

// ---- flash attention helpers (swapped QK^T: S^T = mfma(K, Q), exp2 domain) ----

__device__ __forceinline__ void load_k(const u16* __restrict__ Kp, int k0,
                                       int cl, int kg, bf16x8 kf[8]) {
#pragma unroll
  for (int nt = 0; nt < 4; ++nt) {
    const u16* kp = Kp + (size_t)(k0 + nt * 16 + cl) * Dh + kg * 8;
    kf[nt * 2] = *(const bf16x8*)kp;
    kf[nt * 2 + 1] = *(const bf16x8*)(kp + 32);
  }
}

__device__ __forceinline__ void load_v(const u16* __restrict__ Vp, int k0,
                                       int cl, int kg, bf16x8 vf[8]) {
#pragma unroll
  for (int dt = 0; dt < 4; ++dt) {
    const u16* vp = Vp + (size_t)(dt * 16 + cl) * Tsz + k0 + kg * 8;
    vf[dt * 2] = *(const bf16x8*)vp;
    vf[dt * 2 + 1] = *(const bf16x8*)(vp + 32);
  }
}

__device__ __forceinline__ void qk_tile(const bf16x8 kf[8], const bf16x8& q0,
                                        const bf16x8& q1, f32x4 s[4]) {
  __builtin_amdgcn_s_setprio(1);
#pragma unroll
  for (int nt = 0; nt < 4; ++nt) {
    f32x4 z = {};
    z = MFMA(kf[nt * 2], q0, z);
    z = MFMA(kf[nt * 2 + 1], q1, z);
    s[nt] = z;
  }
  __builtin_amdgcn_s_setprio(0);
}

// Online-softmax (exp2, defer-max, lazy reductions) + P->LDS->A-frag + PV.
// Per-lane q-row = cl; l is a per-lane PARTIAL sum (reduced in epilogue);
// m is row-uniform (only updated inside the rare rescale branch).
template <bool MASK>
__device__ __forceinline__ void sm_pv(f32x4 s[4], float& m, float& l, f32x4 o[4],
                                      const bf16x8 vf[8], char* pb, int rdoff0,
                                      int rdoff1, int cl, int kg, int rowoff) {
  if (MASK) {
#pragma unroll
    for (int nt = 0; nt < 4; ++nt)
#pragma unroll
      for (int j = 0; j < 4; ++j)
        if (nt * 16 + kg * 4 + j > rowoff + cl) s[nt][j] = NEGINF;
  }
  // per-lane partial max (no cross-lane traffic on the common path)
  float tm = fmaxf(fmaxf(fmaxf(s[0][0], s[0][1]), fmaxf(s[0][2], s[0][3])),
                   fmaxf(fmaxf(s[1][0], s[1][1]), fmaxf(s[1][2], s[1][3])));
  tm = fmaxf(tm, fmaxf(fmaxf(fmaxf(s[2][0], s[2][1]), fmaxf(s[2][2], s[2][3])),
                       fmaxf(fmaxf(s[3][0], s[3][1]), fmaxf(s[3][2], s[3][3]))));
  // defer-max: vote on partials (equivalent decision: every row max is a max
  // of lane partials). Rescale only when some row's max exceeds m+8.
  if (!__all(tm <= m + 8.0f)) {
    tm = fmaxf(tm, __shfl_xor(tm, 16));
    tm = fmaxf(tm, __shfl_xor(tm, 32));
    float mnew = fmaxf(m, tm);
    float corr = EXP2(m - mnew);
    m = mnew;
    l *= corr;  // per-lane partial, corr row-uniform -> valid
    float c0 = __shfl(corr, kg * 4 + 0);
    float c1 = __shfl(corr, kg * 4 + 1);
    float c2 = __shfl(corr, kg * 4 + 2);
    float c3 = __shfl(corr, kg * 4 + 3);
#pragma unroll
    for (int dt = 0; dt < 4; ++dt) {
      o[dt][0] *= c0; o[dt][1] *= c1; o[dt][2] *= c2; o[dt][3] *= c3;
    }
  }
  float rs = 0.f;
#pragma unroll
  for (int nt = 0; nt < 4; ++nt)
#pragma unroll
    for (int j = 0; j < 4; ++j) {
      float pv = EXP2(s[nt][j] - m);
      s[nt][j] = pv;
      rs += pv;
    }
  l += rs;  // lazy: cross-lane sum deferred to epilogue
  // P -> LDS rows [q=cl][k], hw cvt_pk, 8B stores, XOR-swizzled
#pragma unroll
  for (int nt = 0; nt < 4; ++nt) {
    uint2 pk;
    pk.x = cvtpk(s[nt][0], s[nt][1]);
    pk.y = cvtpk(s[nt][2], s[nt][3]);
    int waddr = ((cl << 7) + (nt << 5) + (kg << 3)) ^ ((cl & 7) << 4);
    *(uint2*)(pb + waddr) = pk;
  }
  bf16x8 pa0 = *(const bf16x8*)(pb + rdoff0);
  bf16x8 pa1 = *(const bf16x8*)(pb + rdoff1);
  __builtin_amdgcn_s_setprio(1);
#pragma unroll
  for (int dt = 0; dt < 4; ++dt) {
    o[dt] = MFMA(pa0, vf[dt * 2], o[dt]);
    o[dt] = MFMA(pa1, vf[dt * 2 + 1], o[dt]);
  }
  __builtin_amdgcn_s_setprio(0);
}

// Folded flash attention: block handles q-tile pair (tp, 31-tp); dual rowset
// per wave (2 independent chains); K double-buffered in regs; XCD clustering:
// bid&7 = XCD, all blocks of one (b,h) share an XCD (KV stays L2-resident).
__global__ __launch_bounds__(256, 2) void k_attn(const u16* __restrict__ qb,
                                                 const u16* __restrict__ kb,
                                                 const u16* __restrict__ vtb,
                                                 u16* __restrict__ ob) {
  __shared__ __align__(16) u16 Plds[4][2][1024];
  const int lane = threadIdx.x & 63, wid = threadIdx.x >> 6;
  const int cl = lane & 15, kg = lane >> 4;
  const int bid = blockIdx.x;
  const int kdec = bid >> 3;
  const int p = (bid & 7) + ((kdec >> 4) << 3);
  const int tp = kdec & 15;
  const int h = p & 15, b = p >> 4;
  const int tA = tp, tB = 31 - tp;
  const int qrA = tA * 64 + wid * 16;
  const int qrB = tB * 64 + wid * 16;
  const size_t bh = (size_t)(b * Hn + h);
  const u16* Qp = qb + bh * Tsz * Dh;
  const u16* Kp = kb + bh * Tsz * Dh;
  const u16* Vp = vtb + bh * Dh * Tsz;

  bf16x8 qaA0 = *(const bf16x8*)(Qp + (size_t)(qrA + cl) * Dh + kg * 8);
  bf16x8 qaA1 = *(const bf16x8*)(Qp + (size_t)(qrA + cl) * Dh + 32 + kg * 8);
  bf16x8 qaB0 = *(const bf16x8*)(Qp + (size_t)(qrB + cl) * Dh + kg * 8);
  bf16x8 qaB1 = *(const bf16x8*)(Qp + (size_t)(qrB + cl) * Dh + 32 + kg * 8);

  f32x4 oA[4] = {}, oB[4] = {};
  float mA = NEGINF, lA = 0.f, mB = NEGINF, lB = 0.f;

  char* pbA = (char*)&Plds[wid][0][0];
  char* pbB = (char*)&Plds[wid][1][0];
  const int rdoff0 = ((cl << 7) + (kg << 4)) ^ ((cl & 7) << 4);
  const int rdoff1 = ((cl << 7) + 64 + (kg << 4)) ^ ((cl & 7) << 4);
  const int rowoff = wid * 16;

  auto process = [&](int t, const bf16x8 (&kf)[8]) {
    bf16x8 vf[8];
    load_v(Vp, t * 64, cl, kg, vf);
    f32x4 sB[4];
    qk_tile(kf, qaB0, qaB1, sB);
    if (t <= tA) {
      f32x4 sA[4];
      qk_tile(kf, qaA0, qaA1, sA);
      if (t == tA)
        sm_pv<true>(sA, mA, lA, oA, vf, pbA, rdoff0, rdoff1, cl, kg, rowoff);
      else
        sm_pv<false>(sA, mA, lA, oA, vf, pbA, rdoff0, rdoff1, cl, kg, rowoff);
    }
    if (t == tB)
      sm_pv<true>(sB, mB, lB, oB, vf, pbB, rdoff0, rdoff1, cl, kg, rowoff);
    else
      sm_pv<false>(sB, mB, lB, oB, vf, pbB, rdoff0, rdoff1, cl, kg, rowoff);
  };

  const int ntot = tB + 1;
  bf16x8 kf0[8], kf1[8];
  load_k(Kp, 0, cl, kg, kf0);
  int t = 0;
  for (; t + 1 < ntot; t += 2) {
    load_k(Kp, (t + 1) * 64, cl, kg, kf1);
    process(t, kf0);
    if (t + 2 < ntot) load_k(Kp, (t + 2) * 64, cl, kg, kf0);
    process(t + 1, kf1);
  }
  if (t < ntot) process(t, kf0);

  // epilogue: finish lazy l reduction, then broadcast 1/l per O row
  lA += __shfl_xor(lA, 16); lA += __shfl_xor(lA, 32);
  lB += __shfl_xor(lB, 16); lB += __shfl_xor(lB, 32);
  float iA0 = 1.f / __shfl(lA, kg * 4 + 0), iA1 = 1.f / __shfl(lA, kg * 4 + 1);
  float iA2 = 1.f / __shfl(lA, kg * 4 + 2), iA3 = 1.f / __shfl(lA, kg * 4 + 3);
  float iB0 = 1.f / __shfl(lB, kg * 4 + 0), iB1 = 1.f / __shfl(lB, kg * 4 + 1);
  float iB2 = 1.f / __shfl(lB, kg * 4 + 2), iB3 = 1.f / __shfl(lB, kg * 4 + 3);
  float invA[4] = {iA0, iA1, iA2, iA3};
  float invB[4] = {iB0, iB1, iB2, iB3};
#pragma unroll
  for (int dt = 0; dt < 4; ++dt)
#pragma unroll
    for (int j = 0; j < 4; ++j) {
      int ta = qrA + kg * 4 + j;
      int tb = qrB + kg * 4 + j;
      ob[(size_t)(b * Tsz + ta) * Cdim + h * Dh + dt * 16 + cl] = f2bf(oA[dt][j] * invA[j]);
      ob[(size_t)(b * Tsz + tb) * Cdim + h * Dh + dt * 16 + cl] = f2bf(oB[dt][j] * invB[j]);
    }
}

// Out GEMM, 2-phase dbuf: 128x64 tile, BK=32.
__global__ __launch_bounds__(256) void k_gemm_out(const u16* __restrict__ ob,
                                                  const u16* __restrict__ wob,
                                                  const float* __restrict__ bo,
                                                  float* __restrict__ out) {
  __shared__ __align__(16) u16 As[2][4096], Bs[2][2048];
  const int tid = threadIdx.x, lane = tid & 63, wid = tid >> 6;
  const int cl = lane & 15, kg = lane >> 4;
  const int row0 = blockIdx.y * 128, col0 = blockIdx.x * 64;
  const int wrow = (wid >> 1) * 64, wcol = (wid & 1) * 32;
  f32x4 acc[4][2] = {};
  const u16* a_src = ob + (size_t)(row0 + 32 * wid + (lane >> 2)) * Cdim + (lane & 3) * 8;
  const u16* b_src = wob + (size_t)(col0 + 16 * wid + (lane >> 2)) * Cdim + (lane & 3) * 8;

  auto stage = [&](int buf, int ke) {
    u16* Ad = &As[buf][1024 * wid];
    u16* Bd = &Bs[buf][512 * wid];
    GLD16(a_src + ke, Ad);
    GLD16(a_src + 16 * Cdim + ke, Ad + 512);
    GLD16(b_src + ke, Bd);
  };

  stage(0, 0);
  __syncthreads();
  int cur = 0;
  for (int kk = 0; kk < 32; ++kk) {
    if (kk < 31) stage(cur ^ 1, (kk + 1) * 32);
    const u16* ar = &As[cur][(wrow + cl) * 32 + kg * 8];
    const u16* br = &Bs[cur][(wcol + cl) * 32 + kg * 8];
    bf16x8 af[4], bfr[2];
#pragma unroll
    for (int mi = 0; mi < 4; ++mi) af[mi] = *(const bf16x8*)(ar + mi * 512);
#pragma unroll
    for (int ni = 0; ni < 2; ++ni) bfr[ni] = *(const bf16x8*)(br + ni * 512);
#pragma unroll
    for (int mi = 0; mi < 4; ++mi)
#pragma unroll
      for (int ni = 0; ni < 2; ++ni)
        acc[mi][ni] = MFMA(af[mi], bfr[ni], acc[mi][ni]);
    __syncthreads();
    cur ^= 1;
  }
#pragma unroll
  for (int mi = 0; mi < 4; ++mi) {
#pragma unroll
    for (int ni = 0; ni < 2; ++ni) {
      int n = col0 + wcol + ni * 16 + cl;
      float bias = bo[n];
#pragma unroll
      for (int j = 0; j < 4; ++j) {
        int r = row0 + wrow + mi * 16 + kg * 4 + j;
        out[(size_t)r * Cdim + n] = acc[mi][ni][j] + bias;
      }
    }
  }
}

extern "C" void kernel_launch(void* const* d_in, const int* in_sizes, int n_in,
                              void* d_out, int out_size, void* d_ws, size_t ws_size,
                              hipStream_t stream) {
  (void)in_sizes; (void)n_in; (void)out_size; (void)ws_size;
  const float* x = (const float*)d_in[0];
  const float* Wq = (const float*)d_in[1];
  const float* Wk = (const float*)d_in[2];
  const float* Wv = (const float*)d_in[3];
  const float* Wo = (const float*)d_in[4];
  const float* bo = (const float*)d_in[5];
  float* out = (float*)d_out;
  char* ws = (char*)d_ws;
  u16* xb = (u16*)(ws);                  // 8 MiB  x bf16 [4096][1024]
  u16* wt = (u16*)(ws + (8u << 20));     // 6 MiB  Wqkv^T bf16 [3072][1024]
  u16* wob = (u16*)(ws + (14u << 20));   // 2 MiB  Wo bf16 [1024][1024]
  u16* qb = (u16*)(ws + (16u << 20));    // 8 MiB  Q [b][h][t][d] (pre-scaled)
  u16* kb = (u16*)(ws + (24u << 20));    // 8 MiB  K [b][h][t][d]
  u16* vtb = (u16*)(ws + (32u << 20));   // 8 MiB  V^T [b][h][d][t]
  u16* ob = (u16*)(ws + (40u << 20));    // 8 MiB  attn out [b][t][h*64+d]

  k_cast_x<<<4096, 256, 0, stream>>>(x, xb, Bsz * Tsz * Cdim / 4);
  k_cast_x<<<1024, 256, 0, stream>>>(Wo, wob, Cdim * Cdim / 4);
  k_cast_w<<<dim3(16, 48), 256, 0, stream>>>(Wq, Wk, Wv, wt);
  k_gemm_qkv<<<dim3(24, 32), 256, 0, stream>>>(xb, wt, qb, kb, vtb);
  k_attn<<<512, 256, 0, stream>>>(qb, kb, vtb, ob);
  k_gemm_out<<<dim3(16, 32), 256, 0, stream>>>(ob, wob, bo, out);
}